// Round 4
// baseline (839.148 us; speedup 1.0000x reference)
//
#include <hip/hip_runtime.h>

#define SEQ 4096
#define TOK 16384            // B*S
#define DM 1024
#define NQKV 3072
#define FFH 2730
#define FFHP 2816            // padded to multiple of 128

typedef __bf16 bf16x8 __attribute__((ext_vector_type(8)));
typedef float f32x4 __attribute__((ext_vector_type(4)));
typedef unsigned short u16x8 __attribute__((ext_vector_type(8)));

__device__ __forceinline__ unsigned short f2bf(float f) {
  union { float f; unsigned u; } v; v.f = f;
  unsigned r = v.u + 0x7fffu + ((v.u >> 16) & 1u);
  return (unsigned short)(r >> 16);
}
__device__ __forceinline__ float bf2f(unsigned short h) {
  union { unsigned u; float f; } v; v.u = ((unsigned)h) << 16;
  return v.f;
}

__device__ __forceinline__ void xcd_swizzle(int& bx, int& by) {
  const int gx = gridDim.x, gy = gridDim.y;
  const int chunk = gy >> 3;            // power of 2 in all our launches
  const int csh = __ffs(chunk) - 1;
  const int lin = by * gx + bx;
  const int xcd = lin & 7, j = lin >> 3;
  by = xcd * chunk + (j & (chunk - 1));
  bx = j >> csh;
}

enum { M_QKV = 0, M_BF16 = 1, M_NUM = 2, M_BIAS_F32 = 5 };

// ---------------- legacy 128x128 kernel (QKV + kv GEMMs) ----------------
// 32KiB LDS -> 3 blocks/CU resident: QKV's expensive transposed-scatter
// epilogue overlaps other blocks' main loops (unlike 256^2 at 1 block/CU,
// where it is fully latency-exposed).
template<int MODE>
__global__ __launch_bounds__(256)
void gemm_kernel(const unsigned short* __restrict__ A,
                 const unsigned short* __restrict__ BT,
                 int K, int lda, int ldb, int ldc,
                 long zsA, long zsB, long zsC,
                 void* __restrict__ out0, void* __restrict__ out1, void* __restrict__ out2,
                 const float* __restrict__ bias, int nbias)
{
  __shared__ unsigned short As[2][128 * 64];
  __shared__ unsigned short Bs[2][128 * 64];
  const int tid  = threadIdx.x;
  const int wave = tid >> 6, lane = tid & 63;
  const int quad = lane >> 4, l16 = lane & 15;
  const int bz = blockIdx.z;
  int bx = blockIdx.x, by = blockIdx.y;
  xcd_swizzle(bx, by);

  const unsigned short* Ab = A + (size_t)zsA * bz + (size_t)by * 128 * lda;
  const unsigned short* Bb = BT + (size_t)zsB * bz + (size_t)bx * 128 * ldb;

  f32x4 acc[4][4] = {};

  const int srow   = lane >> 3;
  const int scol_g = (((lane & 7) ^ srow) * 8);
  const int axor   = l16 & 7;

  auto stage = [&](int buf, int k0) {
#pragma unroll
    for (int j = 0; j < 4; ++j) {
      int c = wave * 4 + j;
      const unsigned short* sa = Ab + (size_t)(c * 8 + srow) * lda + k0 + scol_g;
      __builtin_amdgcn_global_load_lds((__attribute__((address_space(1))) void*)sa,
          (__attribute__((address_space(3))) void*)(As[buf] + c * 512), 16, 0, 0);
      const unsigned short* sb = Bb + (size_t)(c * 8 + srow) * ldb + k0 + scol_g;
      __builtin_amdgcn_global_load_lds((__attribute__((address_space(1))) void*)sb,
          (__attribute__((address_space(3))) void*)(Bs[buf] + c * 512), 16, 0, 0);
    }
  };

  const int NIT = K >> 6;
  stage(0, 0);
  int cur = 0;
  for (int it = 0; it < NIT; ++it) {
    __builtin_amdgcn_s_waitcnt(0);
    __syncthreads();
    if (it + 1 < NIT) stage(cur ^ 1, (it + 1) << 6);
#pragma unroll
    for (int kk = 0; kk < 64; kk += 32) {
      bf16x8 af[4], bfr[4];
#pragma unroll
      for (int mt = 0; mt < 4; ++mt)
        af[mt] = *(const bf16x8*)(As[cur] + ((wave >> 1) * 64 + mt * 16 + l16) * 64
                                     + ((((kk >> 3) + quad) ^ axor) * 8));
#pragma unroll
      for (int nt = 0; nt < 4; ++nt)
        bfr[nt] = *(const bf16x8*)(Bs[cur] + ((wave & 1) * 64 + nt * 16 + l16) * 64
                                      + ((((kk >> 3) + quad) ^ axor) * 8));
#pragma unroll
      for (int mt = 0; mt < 4; ++mt)
#pragma unroll
        for (int nt = 0; nt < 4; ++nt)
          acc[mt][nt] = __builtin_amdgcn_mfma_f32_16x16x32_bf16(af[mt], bfr[nt], acc[mt][nt], 0, 0, 0);
    }
    cur ^= 1;
  }

#pragma unroll
  for (int mt = 0; mt < 4; ++mt) {
#pragma unroll
    for (int nt = 0; nt < 4; ++nt) {
      const int r0 = by * 128 + (wave >> 1) * 64 + mt * 16 + quad * 4;
      const int c  = bx * 128 + (wave & 1) * 64 + nt * 16 + l16;
      float vals[4];
#pragma unroll
      for (int i = 0; i < 4; ++i) vals[i] = acc[mt][nt][i];

      if (MODE == M_QKV) {
        const int b = r0 >> 12, s0 = r0 & 4095;
#pragma unroll
        for (int i = 0; i < 4; ++i) vals[i] += bias[c];
        if (c < 1024) {
#pragma unroll
          for (int i = 0; i < 4; ++i) {
            float e = vals[i] > 0.f ? vals[i] + 1.f : __expf(vals[i]);
            ((unsigned short*)out0)[(size_t)(r0 + i) * DM + c] = f2bf(e);
          }
        } else if (c < 2048) {
          ushort4 o;
          float e0 = vals[0] > 0.f ? vals[0] + 1.f : __expf(vals[0]);
          float e1 = vals[1] > 0.f ? vals[1] + 1.f : __expf(vals[1]);
          float e2 = vals[2] > 0.f ? vals[2] + 1.f : __expf(vals[2]);
          float e3 = vals[3] > 0.f ? vals[3] + 1.f : __expf(vals[3]);
          o.x = f2bf(e0); o.y = f2bf(e1); o.z = f2bf(e2); o.w = f2bf(e3);
          *(ushort4*)((unsigned short*)out1 + (size_t)b * DM * SEQ + (size_t)(c - 1024) * SEQ + s0) = o;
        } else {
          ushort4 o;
          o.x = f2bf(vals[0]); o.y = f2bf(vals[1]); o.z = f2bf(vals[2]); o.w = f2bf(vals[3]);
          *(ushort4*)((unsigned short*)out2 + (size_t)b * DM * SEQ + (size_t)(c - 2048) * SEQ + s0) = o;
        }
      } else {
#pragma unroll
        for (int i = 0; i < 4; ++i) {
          const int r = r0 + i;
          float val = vals[i];
          if (MODE == M_BF16 || MODE == M_NUM) {
            ((unsigned short*)out0)[(size_t)zsC * bz + (size_t)r * ldc + c] = f2bf(val);
          } else {
            if (c < nbias) val += bias[c];
            ((float*)out0)[(size_t)r * ldc + c] = val;
          }
        }
      }
    }
  }
}

// ---------------- 256x256 8-phase kernel, register-resident K-tile ----------------
// BM=BN=256, BK=64, 8 waves (2M x 4N), per-wave 128x64 output, dbuf LDS 128KiB.
// All 24 ds_read_b128 for a buffer issued at its ENTRY (LDS_ALL); fragments stay
// in registers across the 4 quadrant phases.
// Counted vmcnt at ONLY P4/P8 (m201-faithful): between each stage group and its
// first read exactly 6 newer loads are issued, so vmcnt(6) drains precisely the
// 8 loads the next LDS_ALL needs. Tail iteration (t2s false): P2-P7 issue no
// loads, so the counted wait under-drains -> use vmcnt(0) there (race fix).
// Restage safety: each LDS region's restage phase is >= 1 barrier after the
// phase whose MFMA first consumes (and thus retires) its ds_reads.
enum { G_GATEUP = 0, G_NUM = 1, G_BIAS_F32 = 2 };

#define MBAR() asm volatile("s_barrier" ::: "memory")
#define WAITV(N) asm volatile("s_waitcnt vmcnt(" #N ")" ::: "memory")

// read ALL fragments of buffer BUF: A-quad0, B-quad0 first (phase-entry MFMAs
// wait only on these 12), then A-quad1, B-quad1 (consumed 1-2 phases later).
#define LDS_ALL(BUF) do {                                                     \
    _Pragma("unroll")                                                         \
    for (int mt = 0; mt < 4; ++mt) {                                          \
      _Pragma("unroll")                                                       \
      for (int k2 = 0; k2 < 2; ++k2)                                          \
        af[0][mt][k2] = *(const bf16x8*)(As[BUF] +                            \
            (wm * 128 + mt * 16 + l16) * 64 + (((k2 * 4 + quad) ^ axor) * 8));\
    }                                                                         \
    _Pragma("unroll")                                                         \
    for (int nt = 0; nt < 2; ++nt) {                                          \
      _Pragma("unroll")                                                       \
      for (int k2 = 0; k2 < 2; ++k2)                                          \
        bfr[0][nt][k2] = *(const bf16x8*)(Bs[BUF] +                           \
            (wn * 64 + nt * 16 + l16) * 64 + (((k2 * 4 + quad) ^ axor) * 8)); \
    }                                                                         \
    _Pragma("unroll")                                                         \
    for (int mt = 0; mt < 4; ++mt) {                                          \
      _Pragma("unroll")                                                       \
      for (int k2 = 0; k2 < 2; ++k2)                                          \
        af[1][mt][k2] = *(const bf16x8*)(As[BUF] +                            \
            (wm * 128 + (4 + mt) * 16 + l16) * 64 +                           \
            (((k2 * 4 + quad) ^ axor) * 8));                                  \
    }                                                                         \
    _Pragma("unroll")                                                         \
    for (int nt = 0; nt < 2; ++nt) {                                          \
      _Pragma("unroll")                                                       \
      for (int k2 = 0; k2 < 2; ++k2)                                          \
        bfr[1][nt][k2] = *(const bf16x8*)(Bs[BUF] +                           \
            (wn * 64 + (2 + nt) * 16 + l16) * 64 +                            \
            (((k2 * 4 + quad) ^ axor) * 8));                                  \
    }                                                                         \
  } while (0)

#define MMAQ(QM, QN) do {                                                     \
    _Pragma("unroll")                                                         \
    for (int mt = 0; mt < 4; ++mt) {                                          \
      _Pragma("unroll")                                                       \
      for (int nt = 0; nt < 2; ++nt) {                                        \
        _Pragma("unroll")                                                     \
        for (int k2 = 0; k2 < 2; ++k2)                                        \
          acc[(QM) * 4 + mt][(QN) * 2 + nt] =                                 \
              __builtin_amdgcn_mfma_f32_16x16x32_bf16(af[QM][mt][k2],         \
                  bfr[QN][nt][k2], acc[(QM) * 4 + mt][(QN) * 2 + nt], 0, 0, 0);\
      }                                                                       \
    }                                                                         \
  } while (0)

#define PHASE(QM, QN, STAGE, WAIT) do {                                       \
    STAGE                                                                     \
    MBAR();                                                                   \
    __builtin_amdgcn_sched_barrier(0);                                        \
    __builtin_amdgcn_s_setprio(1);                                            \
    MMAQ(QM, QN);                                                             \
    __builtin_amdgcn_s_setprio(0);                                            \
    WAIT                                                                      \
    MBAR();                                                                   \
  } while (0)

template<int MODE>
__global__ __launch_bounds__(512, 2)
void gemm256_kernel(const unsigned short* __restrict__ A,
                    const unsigned short* __restrict__ BT,
                    int K, int lda, int ldb, int ldc,
                    long zsA, long zsB, long zsC,
                    void* __restrict__ out0,
                    const float* __restrict__ bias0,
                    const float* __restrict__ bias1,
                    int nbias)
{
  __shared__ unsigned short As[2][256 * 64];   // 64 KiB
  __shared__ unsigned short Bs[2][256 * 64];   // 64 KiB
  const int tid  = threadIdx.x;
  const int wave = tid >> 6, lane = tid & 63;
  const int quad = lane >> 4, l16 = lane & 15;
  const int wm = wave >> 2, wn = wave & 3;
  const int bz = blockIdx.z;
  int bx = blockIdx.x, by = blockIdx.y;
  xcd_swizzle(bx, by);

  const unsigned short* Ab = A + (size_t)zsA * bz + (size_t)by * 256 * lda;
  const unsigned short* Bb = BT + (size_t)zsB * bz + (size_t)bx * 256 * ldb;

  f32x4 acc[8][4] = {};

  const int srow = lane >> 3;                 // row within 8-row chunk
  const int sxor = ((lane & 7) ^ srow) * 8;   // pre-swizzled global col block
  const int axor = l16 & 7;

  // Per-wave staging pointers/chunks (2 parts x 2 loads each).
  // A part0 chunks {0-7,16-23} (= quad0 rows of both wm), part1 {8-15,24-31}.
  // B part0 chunks {0-3,8-11,16-19,24-27} (= quad0 cols of all wn), part1 +4.
  const unsigned short* pA[2][2];
  const unsigned short* pB[2][2];
  int cA[2][2], cB[2][2];
#pragma unroll
  for (int part = 0; part < 2; ++part) {
#pragma unroll
    for (int j = 0; j < 2; ++j) {
      int idx = wave * 2 + j;                 // 0..15
      int ca = ((idx & 8) ? idx + 8 : idx) + part * 8;
      int cb = (idx >> 2) * 8 + (idx & 3) + part * 4;
      cA[part][j] = ca; cB[part][j] = cb;
      pA[part][j] = Ab + (size_t)(ca * 8 + srow) * lda + sxor;
      pB[part][j] = Bb + (size_t)(cb * 8 + srow) * ldb + sxor;
    }
  }

  auto stageA = [&](int buf, int part, int tile) {
    const int k0 = tile << 6;
#pragma unroll
    for (int j = 0; j < 2; ++j)
      __builtin_amdgcn_global_load_lds(
          (__attribute__((address_space(1))) void*)(pA[part][j] + k0),
          (__attribute__((address_space(3))) void*)(As[buf] + cA[part][j] * 512), 16, 0, 0);
  };
  auto stageB = [&](int buf, int part, int tile) {
    const int k0 = tile << 6;
#pragma unroll
    for (int j = 0; j < 2; ++j)
      __builtin_amdgcn_global_load_lds(
          (__attribute__((address_space(1))) void*)(pB[part][j] + k0),
          (__attribute__((address_space(3))) void*)(Bs[buf] + cB[part][j] * 512), 16, 0, 0);
  };

  // prologue: buf0 full tile0 (8 loads) + buf1 A0,B0,A1 of tile1 (6 loads)
  stageA(0, 0, 0); stageB(0, 0, 0); stageA(0, 1, 0); stageB(0, 1, 0);
  stageA(1, 0, 1); stageB(1, 0, 1); stageA(1, 1, 1);
  WAITV(6);                      // tile0's 8 loads landed
  MBAR();

  bf16x8 af[2][4][2], bfr[2][2][2];
  const int NT = K >> 6;         // even, >= 4 for all our shapes
  for (int i = 0; i < NT; i += 2) {
    const int t2s = (i + 2 < NT), t3s = (i + 3 < NT);
    // ---- buf0 = tile i ----
    LDS_ALL(0);
    PHASE(0, 0, { stageB(1, 1, i + 1); }, {});                  // P1
    PHASE(1, 0, { if (t2s) stageA(0, 0, i + 2); }, {});         // P2
    PHASE(1, 1, { if (t2s) stageB(0, 0, i + 2); }, {});         // P3
    PHASE(0, 1, { if (t2s) stageA(0, 1, i + 2); },
                { if (t2s) { WAITV(6); } else { WAITV(0); } }); // P4
    // ---- buf1 = tile i+1 ----
    LDS_ALL(1);
    PHASE(0, 0, { if (t2s) stageB(0, 1, i + 2); }, {});         // P5
    PHASE(1, 0, { if (t3s) stageA(1, 0, i + 3); }, {});         // P6
    PHASE(1, 1, { if (t3s) stageB(1, 0, i + 3); }, {});         // P7
    PHASE(0, 1, { if (t3s) stageA(1, 1, i + 3); },
                { if (t2s) { WAITV(6); } else { WAITV(0); } }); // P8
  }

  // ---- epilogue ----
  if (MODE == G_GATEUP) {
    // BT is 16-col-interleaved [gate16|up16]*; n-frag pairs (0,1),(2,3) hold
    // matching gate/up columns -> silu(g)*u is wave-local.
    // LDS-transposed store: bf16 results staged in As (256r x 128c x 2B =
    // 64KiB exactly), XOR-swizzled (quad -> distinct 8-bank group, conflict-
    // free), then 16B-coalesced global stores (256B/row per 16 lanes; kills
    // the 2B-scalar half-line RMW amplification measured at +34MB WRITE).
    unsigned short* lf16 = (unsigned short*)As;
#pragma unroll
    for (int mt = 0; mt < 8; ++mt) {
      const int rloc = wm * 128 + mt * 16 + quad * 4;
#pragma unroll
      for (int p = 0; p < 2; ++p) {
        const int cloc = wn * 32 + p * 16 + l16;      // 0..127
        const int hc = bx * 128 + cloc;
        const float bgv = (hc < nbias) ? bias0[hc] : 0.f;
        const float buv = (hc < nbias) ? bias1[hc] : 0.f;
#pragma unroll
        for (int i2 = 0; i2 < 4; ++i2) {
          float g = acc[mt][2 * p][i2] + bgv;
          float u = acc[mt][2 * p + 1][i2] + buv;
          float hv = g / (1.f + __expf(-g)) * u;
          const int r = rloc + i2;
          lf16[r * 128 + (cloc ^ (((r >> 2) & 3) << 4))] = f2bf(hv);
        }
      }
    }
    __syncthreads();
    {
      const int cb = (tid & 15) * 8;              // col base (8-aligned)
      const int rb = (tid >> 4) * 8;              // row base
#pragma unroll
      for (int j = 0; j < 8; ++j) {
        const int r = rb + j;
        const int cs = cb ^ (((r >> 2) & 3) << 4);
        u16x8 v = *(const u16x8*)(lf16 + r * 128 + cs);
        *(u16x8*)((unsigned short*)out0 + (size_t)(by * 256 + r) * ldc + bx * 128 + cb) = v;
      }
    }
  } else {
#pragma unroll
    for (int mt = 0; mt < 8; ++mt) {
#pragma unroll
      for (int nt = 0; nt < 4; ++nt) {
        const int r0 = by * 256 + wm * 128 + mt * 16 + quad * 4;
        const int c  = bx * 256 + wn * 64 + nt * 16 + l16;
#pragma unroll
        for (int i2 = 0; i2 < 4; ++i2) {
          float v = acc[mt][nt][i2];
          if (MODE == G_NUM) {
            ((unsigned short*)out0)[(size_t)zsC * bz + (size_t)(r0 + i2) * ldc + c] = f2bf(v);
          } else {  // G_BIAS_F32
            if (c < nbias) v += bias0[c];
            ((float*)out0)[(size_t)(r0 + i2) * ldc + c] = v;
          }
        }
      }
    }
  }
}

// fp32 -> bf16 convert, 4 elems/thread
__global__ __launch_bounds__(256)
void cvt_kernel(const float* __restrict__ in, unsigned short* __restrict__ out, int n)
{
  int i = (blockIdx.x * 256 + threadIdx.x) * 4;
  if (i < n) {
    float4 v = *(const float4*)(in + i);
    ushort4 o;
    o.x = f2bf(v.x); o.y = f2bf(v.y); o.z = f2bf(v.z); o.w = f2bf(v.w);
    *(ushort4*)(out + i) = o;
  }
}

// in fp32 [R][C] -> out bf16 [Cpad][Rpad], zero-filled pad. grid (Rpad/32, Cpad/32)
// omode 0: out row = c. omode 1/2: 16-col interleave (gate/up halves of WguT).
__global__ __launch_bounds__(256)
void wtrans_kernel(const float* __restrict__ in, unsigned short* __restrict__ out,
                   int R, int C, int Cpad, int Rpad, int omode)
{
  __shared__ float tile[32][33];
  int r0 = blockIdx.x * 32;   // in-row / out-col
  int c0 = blockIdx.y * 32;   // in-col / out-row
  int tid = threadIdx.x;
#pragma unroll
  for (int j = 0; j < 4; ++j) {
    int r = j * 8 + (tid >> 5), c = tid & 31;
    float v = 0.f;
    if (r0 + r < R && c0 + c < C) v = in[(size_t)(r0 + r) * C + c0 + c];
    tile[r][c] = v;
  }
  __syncthreads();
#pragma unroll
  for (int j = 0; j < 4; ++j) {
    int c = j * 8 + (tid >> 5), r = tid & 31;
    int oc = c0 + c;
    int orow = (omode == 0) ? oc
             : ((oc >> 4) * 32 + (oc & 15) + ((omode == 2) ? 16 : 0));
    out[(size_t)orow * Rpad + (r0 + r)] = f2bf(tile[r][c]);
  }
}

__device__ __forceinline__ float block_sum(float v, float* sm)
{
#pragma unroll
  for (int o = 32; o > 0; o >>= 1) v += __shfl_down(v, o, 64);
  int w = threadIdx.x >> 6;
  if ((threadIdx.x & 63) == 0) sm[w] = v;
  __syncthreads();
  float r = sm[0] + sm[1] + sm[2] + sm[3];
  __syncthreads();
  return r;
}

// row sums of kpT [4][1024][4096] -> ksum [4][1024]; grid 4096
__global__ __launch_bounds__(256)
void ksum_kernel(const unsigned short* __restrict__ kpT, float* __restrict__ ksum)
{
  __shared__ float sm[4];
  int row = blockIdx.x;
  const ushort4* src = (const ushort4*)(kpT + (size_t)row * SEQ);
  float s = 0.f;
#pragma unroll
  for (int j = 0; j < 4; ++j) {
    ushort4 v = src[threadIdx.x + j * 256];
    s += bf2f(v.x) + bf2f(v.y) + bf2f(v.z) + bf2f(v.w);
  }
  float tot = block_sum(s, sm);
  if (threadIdx.x == 0) ksum[row] = tot;
}

// y = LN(x + num/(den+eps)); den = qp . ksum  (fused). grid TOK, 256 thr
__global__ __launch_bounds__(256)
void ln1_kernel(const unsigned short* __restrict__ xb16, const unsigned short* __restrict__ num16,
                const unsigned short* __restrict__ qp, const float* __restrict__ ksum,
                const float* __restrict__ g1, const float* __restrict__ b1,
                unsigned short* __restrict__ yb)
{
  __shared__ float sm[4];
  int t = blockIdx.x, tid = threadIdx.x, b = t >> 12;
  ushort4 xv = ((const ushort4*)(xb16 + (size_t)t * DM))[tid];
  ushort4 nv = ((const ushort4*)(num16 + (size_t)t * DM))[tid];
  ushort4 qv = ((const ushort4*)(qp + (size_t)t * DM))[tid];
  float4 kv = ((const float4*)(ksum + (size_t)b * DM))[tid];
  float q0 = bf2f(qv.x), q1 = bf2f(qv.y), q2 = bf2f(qv.z), q3 = bf2f(qv.w);
  float den = block_sum(q0 * kv.x + q1 * kv.y + q2 * kv.z + q3 * kv.w, sm);
  float inv = 1.f / (den + 1e-6f);
  float r0 = bf2f(xv.x) + bf2f(nv.x) * inv, r1 = bf2f(xv.y) + bf2f(nv.y) * inv;
  float r2 = bf2f(xv.z) + bf2f(nv.z) * inv, r3 = bf2f(xv.w) + bf2f(nv.w) * inv;
  float s1 = block_sum(r0 + r1 + r2 + r3, sm);
  float s2 = block_sum(r0 * r0 + r1 * r1 + r2 * r2 + r3 * r3, sm);
  float mu = s1 * (1.f / 1024.f);
  float var = s2 * (1.f / 1024.f) - mu * mu;
  float rs = rsqrtf(var + 1e-5f);
  float4 gv = ((const float4*)g1)[tid];
  float4 bv = ((const float4*)b1)[tid];
  ushort4 o;
  o.x = f2bf((r0 - mu) * rs * gv.x + bv.x);
  o.y = f2bf((r1 - mu) * rs * gv.y + bv.y);
  o.z = f2bf((r2 - mu) * rs * gv.z + bv.z);
  o.w = f2bf((r3 - mu) * rs * gv.w + bv.w);
  ((ushort4*)(yb + (size_t)t * DM))[tid] = o;
}

// out = LN(y + ffn). grid TOK, 256 thr. ffn may alias out (row-local).
__global__ __launch_bounds__(256)
void ln2_kernel(const unsigned short* __restrict__ yb, const float* __restrict__ ffn,
                const float* __restrict__ g2, const float* __restrict__ b2,
                float* __restrict__ out)
{
  __shared__ float sm[4];
  int t = blockIdx.x, tid = threadIdx.x;
  ushort4 yv = ((const ushort4*)(yb + (size_t)t * DM))[tid];
  float4 fv = ((const float4*)(ffn + (size_t)t * DM))[tid];
  float r0 = bf2f(yv.x) + fv.x, r1 = bf2f(yv.y) + fv.y;
  float r2 = bf2f(yv.z) + fv.z, r3 = bf2f(yv.w) + fv.w;
  float s1 = block_sum(r0 + r1 + r2 + r3, sm);
  float s2 = block_sum(r0 * r0 + r1 * r1 + r2 * r2 + r3 * r3, sm);
  float mu = s1 * (1.f / 1024.f);
  float var = s2 * (1.f / 1024.f) - mu * mu;
  float rs = rsqrtf(var + 1e-5f);
  float4 gv = ((const float4*)g2)[tid];
  float4 bv = ((const float4*)b2)[tid];
  float4 o;
  o.x = (r0 - mu) * rs * gv.x + bv.x;
  o.y = (r1 - mu) * rs * gv.y + bv.y;
  o.z = (r2 - mu) * rs * gv.z + bv.z;
  o.w = (r3 - mu) * rs * gv.w + bv.w;
  ((float4*)(out + (size_t)t * DM))[tid] = o;
}

extern "C" void kernel_launch(void* const* d_in, const int* in_sizes, int n_in,
                              void* d_out, int out_size, void* d_ws, size_t ws_size,
                              hipStream_t stream)
{
  const float* x    = (const float*)d_in[0];
  const float* Wqkv = (const float*)d_in[1];
  const float* bqkv = (const float*)d_in[2];
  const float* Wg   = (const float*)d_in[3];
  const float* bg   = (const float*)d_in[4];
  const float* Wu   = (const float*)d_in[5];
  const float* bu   = (const float*)d_in[6];
  const float* Wd   = (const float*)d_in[7];
  const float* bd   = (const float*)d_in[8];
  const float* g1   = (const float*)d_in[9];
  const float* b1   = (const float*)d_in[10];
  const float* g2   = (const float*)d_in[11];
  const float* b2   = (const float*)d_in[12];
  float* out = (float*)d_out;

  // ---- workspace layout (~158.5 MiB total) ----
  char* ws = (char*)d_ws;
  size_t off = 0;
  auto alloc = [&](size_t bytes) {
    char* p = ws + off;
    off += (bytes + 255) & ~(size_t)255;
    return p;
  };
  unsigned short* WqkvT = (unsigned short*)alloc((size_t)NQKV * DM * 2);      //  6.3 MB
  unsigned short* WguT  = (unsigned short*)alloc((size_t)2 * FFHP * DM * 2);  // 11.5 MB (gate/up 16-col interleaved)
  unsigned short* WdT   = (unsigned short*)alloc((size_t)DM * FFHP * 2);      //  5.8 MB
  float*          ksum  = (float*)alloc((size_t)4 * DM * 4);                  // 16 KB
  unsigned short* xbyb  = (unsigned short*)alloc((size_t)TOK * DM * 2);       // 32 MB (xb then yb)
  unsigned short* kvT   = (unsigned short*)alloc((size_t)4 * DM * DM * 2);    //  8.4 MB
  char* R3 = alloc((size_t)3 * TOK * DM * 2);                                 // 96 MB
  unsigned short* qp  = (unsigned short*)(R3);
  unsigned short* kpT = (unsigned short*)(R3 + (size_t)TOK * DM * 2);
  unsigned short* vT  = (unsigned short*)(R3 + (size_t)2 * TOK * DM * 2);
  unsigned short* hbuf = (unsigned short*)(R3);     // [TOK][FFHP] 92.3 MB, aliases qp/kpT/vT (dead after ln1)
  unsigned short* xb = xbyb;
  unsigned short* yb = xbyb;
  unsigned short* num = (unsigned short*)d_out;     // bf16 scratch in d_out; dead after ln1
  float* ffn = (float*)d_out;                       // fp32 scratch; ln2 reads+overwrites row-local

  dim3 blk(256), blk5(512);

  // 1. x -> bf16
  cvt_kernel<<<dim3(TOK * DM / 1024), blk, 0, stream>>>(x, xb, TOK * DM);
  // 2. weight transpose+convert (+pad; gate/up interleaved into WguT)
  wtrans_kernel<<<dim3(32, 96), blk, 0, stream>>>(Wqkv, WqkvT, 1024, 3072, 3072, 1024, 0);
  wtrans_kernel<<<dim3(32, 88), blk, 0, stream>>>(Wg, WguT, 1024, FFH, FFHP, 1024, 1);
  wtrans_kernel<<<dim3(32, 88), blk, 0, stream>>>(Wu, WguT, 1024, FFH, FFHP, 1024, 2);
  wtrans_kernel<<<dim3(88, 32), blk, 0, stream>>>(Wd, WdT, FFH, 1024, 1024, FFHP, 0);
  // 3. QKV GEMM: qp[s][d] (elu+1), kpT[d][s] (elu+1), vT[d][s]  [128^2 legacy:
  //    3 blocks/CU hides the transposed-scatter epilogue]
  gemm_kernel<M_QKV><<<dim3(NQKV / 128, TOK / 128), blk, 0, stream>>>(
      xb, WqkvT, 1024, 1024, 1024, 0, 0, 0, 0, qp, kpT, vT, bqkv, NQKV);
  // 4. k_sum[b][d]
  ksum_kernel<<<dim3(4096), blk, 0, stream>>>(kpT, ksum);
  // 5. kvT[b][e][d] = sum_s v[s,e] kp[s,d]   [128^2 legacy]
  gemm_kernel<M_BF16><<<dim3(8, 8, 4), blk, 0, stream>>>(
      vT, kpT, 4096, 4096, 4096, 1024,
      (long)DM * SEQ, (long)DM * SEQ, (long)DM * DM,
      kvT, nullptr, nullptr, nullptr, 0);
  // 6. num[b][s][e] = qp[s,:] . kv[:,e]  (BT = kvT) -> d_out (bf16)  [256^2 8-phase]
  gemm256_kernel<G_NUM><<<dim3(4, 16, 4), blk5, 0, stream>>>(
      qp, kvT, 1024, 1024, 1024, 1024,
      (long)SEQ * DM, (long)DM * DM, (long)SEQ * DM,
      num, nullptr, nullptr, 0);
  // 7. LN1 (fused den + attn + residual), y in bf16 (overwrites xb in place)
  ln1_kernel<<<dim3(TOK), blk, 0, stream>>>(xb, num, qp, ksum, g1, b1, yb);
  // 8. h = silu(y@Wg+bg) * (y@Wu+bu), fused 256^2 8-phase over interleaved WguT
  gemm256_kernel<G_GATEUP><<<dim3(2 * FFHP / 256, TOK / 256), blk5, 0, stream>>>(
      yb, WguT, 1024, DM, DM, FFHP, 0, 0, 0, hbuf, bg, bu, FFH);
  // 9. ffn = h @ Wd + bd (fp32) -> d_out  [256^2 8-phase]
  gemm256_kernel<G_BIAS_F32><<<dim3(DM / 256, TOK / 256), blk5, 0, stream>>>(
      hbuf, WdT, FFHP, FFHP, FFHP, DM, 0, 0, 0, ffn, bd, nullptr, DM);
  // 10. out = LN(y + ffn)  (reads+overwrites d_out row-locally)
  ln2_kernel<<<dim3(TOK), blk, 0, stream>>>(yb, ffn, g2, b2, out);

  (void)in_sizes; (void)n_in; (void)out_size; (void)ws_size;
}

// Round 5
// 787.716 us; speedup vs baseline: 1.0653x; 1.0653x over previous
//
#include <hip/hip_runtime.h>

#define SEQ 4096
#define TOK 16384            // B*S
#define DM 1024
#define NQKV 3072
#define FFH 2730
#define FFHP 2816            // padded to multiple of 128

typedef __bf16 bf16x8 __attribute__((ext_vector_type(8)));
typedef float f32x4 __attribute__((ext_vector_type(4)));

__device__ __forceinline__ unsigned short f2bf(float f) {
  union { float f; unsigned u; } v; v.f = f;
  unsigned r = v.u + 0x7fffu + ((v.u >> 16) & 1u);
  return (unsigned short)(r >> 16);
}
__device__ __forceinline__ float bf2f(unsigned short h) {
  union { unsigned u; float f; } v; v.u = ((unsigned)h) << 16;
  return v.f;
}

__device__ __forceinline__ void xcd_swizzle(int& bx, int& by) {
  const int gx = gridDim.x, gy = gridDim.y;
  const int chunk = gy >> 3;            // power of 2 in all our launches
  const int csh = __ffs(chunk) - 1;
  const int lin = by * gx + bx;
  const int xcd = lin & 7, j = lin >> 3;
  by = xcd * chunk + (j & (chunk - 1));
  bx = j >> csh;
}

enum { M_QKV = 0, M_BF16 = 1, M_NUM = 2, M_BIAS_F32 = 5 };

// ---------------- legacy 128x128 kernel (QKV + kv GEMMs) ----------------
// 32KiB LDS -> 3 blocks/CU resident: QKV's expensive transposed-scatter
// epilogue overlaps other blocks' main loops.
template<int MODE>
__global__ __launch_bounds__(256)
void gemm_kernel(const unsigned short* __restrict__ A,
                 const unsigned short* __restrict__ BT,
                 int K, int lda, int ldb, int ldc,
                 long zsA, long zsB, long zsC,
                 void* __restrict__ out0, void* __restrict__ out1, void* __restrict__ out2,
                 const float* __restrict__ bias, int nbias)
{
  __shared__ unsigned short As[2][128 * 64];
  __shared__ unsigned short Bs[2][128 * 64];
  const int tid  = threadIdx.x;
  const int wave = tid >> 6, lane = tid & 63;
  const int quad = lane >> 4, l16 = lane & 15;
  const int bz = blockIdx.z;
  int bx = blockIdx.x, by = blockIdx.y;
  xcd_swizzle(bx, by);

  const unsigned short* Ab = A + (size_t)zsA * bz + (size_t)by * 128 * lda;
  const unsigned short* Bb = BT + (size_t)zsB * bz + (size_t)bx * 128 * ldb;

  f32x4 acc[4][4] = {};

  const int srow   = lane >> 3;
  const int scol_g = (((lane & 7) ^ srow) * 8);
  const int axor   = l16 & 7;

  auto stage = [&](int buf, int k0) {
#pragma unroll
    for (int j = 0; j < 4; ++j) {
      int c = wave * 4 + j;
      const unsigned short* sa = Ab + (size_t)(c * 8 + srow) * lda + k0 + scol_g;
      __builtin_amdgcn_global_load_lds((__attribute__((address_space(1))) void*)sa,
          (__attribute__((address_space(3))) void*)(As[buf] + c * 512), 16, 0, 0);
      const unsigned short* sb = Bb + (size_t)(c * 8 + srow) * ldb + k0 + scol_g;
      __builtin_amdgcn_global_load_lds((__attribute__((address_space(1))) void*)sb,
          (__attribute__((address_space(3))) void*)(Bs[buf] + c * 512), 16, 0, 0);
    }
  };

  const int NIT = K >> 6;
  stage(0, 0);
  int cur = 0;
  for (int it = 0; it < NIT; ++it) {
    __builtin_amdgcn_s_waitcnt(0);
    __syncthreads();
    if (it + 1 < NIT) stage(cur ^ 1, (it + 1) << 6);
#pragma unroll
    for (int kk = 0; kk < 64; kk += 32) {
      bf16x8 af[4], bfr[4];
#pragma unroll
      for (int mt = 0; mt < 4; ++mt)
        af[mt] = *(const bf16x8*)(As[cur] + ((wave >> 1) * 64 + mt * 16 + l16) * 64
                                     + ((((kk >> 3) + quad) ^ axor) * 8));
#pragma unroll
      for (int nt = 0; nt < 4; ++nt)
        bfr[nt] = *(const bf16x8*)(Bs[cur] + ((wave & 1) * 64 + nt * 16 + l16) * 64
                                      + ((((kk >> 3) + quad) ^ axor) * 8));
#pragma unroll
      for (int mt = 0; mt < 4; ++mt)
#pragma unroll
        for (int nt = 0; nt < 4; ++nt)
          acc[mt][nt] = __builtin_amdgcn_mfma_f32_16x16x32_bf16(af[mt], bfr[nt], acc[mt][nt], 0, 0, 0);
    }
    cur ^= 1;
  }

#pragma unroll
  for (int mt = 0; mt < 4; ++mt) {
#pragma unroll
    for (int nt = 0; nt < 4; ++nt) {
      const int r0 = by * 128 + (wave >> 1) * 64 + mt * 16 + quad * 4;
      const int c  = bx * 128 + (wave & 1) * 64 + nt * 16 + l16;
      float vals[4];
#pragma unroll
      for (int i = 0; i < 4; ++i) vals[i] = acc[mt][nt][i];

      if (MODE == M_QKV) {
        const int b = r0 >> 12, s0 = r0 & 4095;
#pragma unroll
        for (int i = 0; i < 4; ++i) vals[i] += bias[c];
        if (c < 1024) {
#pragma unroll
          for (int i = 0; i < 4; ++i) {
            float e = vals[i] > 0.f ? vals[i] + 1.f : __expf(vals[i]);
            ((unsigned short*)out0)[(size_t)(r0 + i) * DM + c] = f2bf(e);
          }
        } else if (c < 2048) {
          ushort4 o;
          float e0 = vals[0] > 0.f ? vals[0] + 1.f : __expf(vals[0]);
          float e1 = vals[1] > 0.f ? vals[1] + 1.f : __expf(vals[1]);
          float e2 = vals[2] > 0.f ? vals[2] + 1.f : __expf(vals[2]);
          float e3 = vals[3] > 0.f ? vals[3] + 1.f : __expf(vals[3]);
          o.x = f2bf(e0); o.y = f2bf(e1); o.z = f2bf(e2); o.w = f2bf(e3);
          *(ushort4*)((unsigned short*)out1 + (size_t)b * DM * SEQ + (size_t)(c - 1024) * SEQ + s0) = o;
        } else {
          ushort4 o;
          o.x = f2bf(vals[0]); o.y = f2bf(vals[1]); o.z = f2bf(vals[2]); o.w = f2bf(vals[3]);
          *(ushort4*)((unsigned short*)out2 + (size_t)b * DM * SEQ + (size_t)(c - 2048) * SEQ + s0) = o;
        }
      } else {
#pragma unroll
        for (int i = 0; i < 4; ++i) {
          const int r = r0 + i;
          float val = vals[i];
          if (MODE == M_BF16 || MODE == M_NUM) {
            ((unsigned short*)out0)[(size_t)zsC * bz + (size_t)r * ldc + c] = f2bf(val);
          } else {
            if (c < nbias) val += bias[c];
            ((float*)out0)[(size_t)r * ldc + c] = val;
          }
        }
      }
    }
  }
}

// ---------------- 256x256 8-phase kernel (R1 structure + counted vmcnt) -------
// BM=BN=256, BK=64, 8 waves (2M x 4N), per-wave 128x64 output, dbuf LDS 128KiB.
// Per-phase ds_reads (R1 style; VGPR-light), Gray-coded quadrants.
// T4 change vs R1: vmcnt wait at ONLY P4/P8. Derived from R1's stage slots:
// at P4, outstanding groups (oldest first) = B0'(buf1),A1'(buf1),A0(buf1),
// B1(buf1),B0(t+2),A1(t+2) = 12 loads; P5-P7 need through B1 landed ->
// WAITV(4). Symmetric at P8. Tail iteration (t2s false): stages missing ->
// counted wait under-drains -> WAITV(0) (fixes R1's latent tail race).
enum { G_GATEUP = 0, G_NUM = 1, G_BIAS_F32 = 2 };

#define MBAR() asm volatile("s_barrier" ::: "memory")
#define WAITV(N) asm volatile("s_waitcnt vmcnt(" #N ")" ::: "memory")

#define LDS_A(BUF, QM) do {                                                   \
    _Pragma("unroll")                                                         \
    for (int mt = 0; mt < 4; ++mt) {                                          \
      _Pragma("unroll")                                                       \
      for (int k2 = 0; k2 < 2; ++k2)                                          \
        af[mt][k2] = *(const bf16x8*)(As[BUF] +                               \
            (wm * 128 + ((QM) * 4 + mt) * 16 + l16) * 64 +                    \
            (((k2 * 4 + quad) ^ axor) * 8));                                  \
    }                                                                         \
  } while (0)

#define LDS_B(BUF, QN) do {                                                   \
    _Pragma("unroll")                                                         \
    for (int nt = 0; nt < 2; ++nt) {                                          \
      _Pragma("unroll")                                                       \
      for (int k2 = 0; k2 < 2; ++k2)                                          \
        bfr[nt][k2] = *(const bf16x8*)(Bs[BUF] +                              \
            (wn * 64 + ((QN) * 2 + nt) * 16 + l16) * 64 +                     \
            (((k2 * 4 + quad) ^ axor) * 8));                                  \
    }                                                                         \
  } while (0)

#define MMAQ(QM, QN) do {                                                     \
    _Pragma("unroll")                                                         \
    for (int mt = 0; mt < 4; ++mt) {                                          \
      _Pragma("unroll")                                                       \
      for (int nt = 0; nt < 2; ++nt) {                                        \
        _Pragma("unroll")                                                     \
        for (int k2 = 0; k2 < 2; ++k2)                                        \
          acc[(QM) * 4 + mt][(QN) * 2 + nt] =                                 \
              __builtin_amdgcn_mfma_f32_16x16x32_bf16(af[mt][k2], bfr[nt][k2],\
                  acc[(QM) * 4 + mt][(QN) * 2 + nt], 0, 0, 0);                \
      }                                                                       \
    }                                                                         \
  } while (0)

#define PHASE(BUF, QM, QN, LA, LB, STAGE, WAIT) do {                          \
    if (LA) LDS_A(BUF, QM);                                                   \
    if (LB) LDS_B(BUF, QN);                                                   \
    STAGE                                                                     \
    MBAR();                                                                   \
    __builtin_amdgcn_sched_barrier(0);                                        \
    __builtin_amdgcn_s_setprio(1);                                            \
    MMAQ(QM, QN);                                                             \
    __builtin_amdgcn_s_setprio(0);                                            \
    WAIT                                                                      \
    MBAR();                                                                   \
  } while (0)

template<int MODE>
__global__ __launch_bounds__(512, 2)
void gemm256_kernel(const unsigned short* __restrict__ A,
                    const unsigned short* __restrict__ BT,
                    int K, int lda, int ldb, int ldc,
                    long zsA, long zsB, long zsC,
                    void* __restrict__ out0,
                    const float* __restrict__ bias0,
                    const float* __restrict__ bias1,
                    int nbias)
{
  __shared__ unsigned short As[2][256 * 64];   // 64 KiB
  __shared__ unsigned short Bs[2][256 * 64];   // 64 KiB
  const int tid  = threadIdx.x;
  const int wave = tid >> 6, lane = tid & 63;
  const int quad = lane >> 4, l16 = lane & 15;
  const int wm = wave >> 2, wn = wave & 3;
  const int bz = blockIdx.z;
  int bx = blockIdx.x, by = blockIdx.y;
  xcd_swizzle(bx, by);

  const unsigned short* Ab = A + (size_t)zsA * bz + (size_t)by * 256 * lda;
  const unsigned short* Bb = BT + (size_t)zsB * bz + (size_t)bx * 256 * ldb;

  f32x4 acc[8][4] = {};

  const int srow = lane >> 3;                 // row within 8-row chunk
  const int sxor = ((lane & 7) ^ srow) * 8;   // pre-swizzled global col block
  const int axor = l16 & 7;

  // Per-wave staging pointers/chunks (2 parts x 2 loads each).
  // A part0 chunks {0-7,16-23} (= quad0 rows of both wm), part1 {8-15,24-31}.
  // B part0 chunks {0-3,8-11,16-19,24-27} (= quad0 cols of all wn), part1 +4.
  const unsigned short* pA[2][2];
  const unsigned short* pB[2][2];
  int cA[2][2], cB[2][2];
#pragma unroll
  for (int part = 0; part < 2; ++part) {
#pragma unroll
    for (int j = 0; j < 2; ++j) {
      int idx = wave * 2 + j;                 // 0..15
      int ca = ((idx & 8) ? idx + 8 : idx) + part * 8;
      int cb = (idx >> 2) * 8 + (idx & 3) + part * 4;
      cA[part][j] = ca; cB[part][j] = cb;
      pA[part][j] = Ab + (size_t)(ca * 8 + srow) * lda + sxor;
      pB[part][j] = Bb + (size_t)(cb * 8 + srow) * ldb + sxor;
    }
  }

  auto stageA = [&](int buf, int part, int tile) {
    const int k0 = tile << 6;
#pragma unroll
    for (int j = 0; j < 2; ++j)
      __builtin_amdgcn_global_load_lds(
          (__attribute__((address_space(1))) void*)(pA[part][j] + k0),
          (__attribute__((address_space(3))) void*)(As[buf] + cA[part][j] * 512), 16, 0, 0);
  };
  auto stageB = [&](int buf, int part, int tile) {
    const int k0 = tile << 6;
#pragma unroll
    for (int j = 0; j < 2; ++j)
      __builtin_amdgcn_global_load_lds(
          (__attribute__((address_space(1))) void*)(pB[part][j] + k0),
          (__attribute__((address_space(3))) void*)(Bs[buf] + cB[part][j] * 512), 16, 0, 0);
  };

  // prologue: tile0 full (8 loads), tile1 B0+A1 (4 loads)
  stageA(0, 0, 0); stageA(0, 1, 0); stageB(0, 0, 0); stageB(0, 1, 0);
  stageB(1, 0, 1); stageA(1, 1, 1);
  WAITV(4);                      // tile0 (oldest 8 loads) landed
  MBAR();

  bf16x8 af[4][2], bfr[2][2];
  const int NT = K >> 6;         // even, >= 4 for all our shapes
  for (int i = 0; i < NT; i += 2) {
    const int t1 = i + 1;
    const int t2s = (i + 2 < NT), t3s = (i + 3 < NT);
    // buf0 = tile i, quadrants in Gray order; buf1 = tile i+1
    PHASE(0, 0, 0, 1, 1, { stageA(1, 0, t1); }, {});                 // P1: +A0(t+1)
    PHASE(0, 1, 0, 1, 0, { stageB(1, 1, t1); }, {});                 // P2: +B1(t+1)
    PHASE(0, 1, 1, 0, 1, { if (t2s) stageB(0, 0, i + 2); }, {});     // P3: +B0(t+2)
    PHASE(0, 0, 1, 1, 0, { if (t2s) stageA(0, 1, i + 2); },
                         { if (t2s) { WAITV(4); } else { WAITV(0); } }); // P4: +A1(t+2)
    PHASE(1, 0, 0, 1, 1, { if (t2s) stageA(0, 0, i + 2); }, {});     // P5: +A0(t+2)
    PHASE(1, 1, 0, 1, 0, { if (t2s) stageB(0, 1, i + 2); }, {});     // P6: +B1(t+2)
    PHASE(1, 1, 1, 0, 1, { if (t3s) stageB(1, 0, i + 3); }, {});     // P7: +B0(t+3)
    PHASE(1, 0, 1, 1, 0, { if (t3s) stageA(1, 1, i + 3); },
                         { if (t3s) { WAITV(4); } else { WAITV(0); } }); // P8: +A1(t+3)
  }

  // ---- epilogue (R1's verified-clean versions) ----
  if (MODE == G_GATEUP) {
    // BT is 16-col-interleaved [gate16|up16]*; n-frag pairs (0,1),(2,3) hold
    // matching gate/up columns -> silu(g)*u is wave-local.
#pragma unroll
    for (int mt = 0; mt < 8; ++mt) {
      const int r0 = by * 256 + wm * 128 + mt * 16 + quad * 4;
#pragma unroll
      for (int p = 0; p < 2; ++p) {
        const int hc = bx * 128 + wn * 32 + p * 16 + l16;
        const float bgv = (hc < nbias) ? bias0[hc] : 0.f;
        const float buv = (hc < nbias) ? bias1[hc] : 0.f;
#pragma unroll
        for (int i2 = 0; i2 < 4; ++i2) {
          float g = acc[mt][2 * p][i2] + bgv;
          float u = acc[mt][2 * p + 1][i2] + buv;
          float hv = g / (1.f + __expf(-g)) * u;
          ((unsigned short*)out0)[(size_t)(r0 + i2) * ldc + hc] = f2bf(hv);
        }
      }
    }
  } else {
#pragma unroll
    for (int mt = 0; mt < 8; ++mt) {
#pragma unroll
      for (int nt = 0; nt < 4; ++nt) {
        const int r0 = by * 256 + wm * 128 + mt * 16 + quad * 4;
        const int c  = bx * 256 + wn * 64 + nt * 16 + l16;
#pragma unroll
        for (int i2 = 0; i2 < 4; ++i2) {
          float v = acc[mt][nt][i2];
          if (MODE == G_NUM) {
            ((unsigned short*)out0)[(size_t)zsC * bz + (size_t)(r0 + i2) * ldc + c] = f2bf(v);
          } else {  // G_BIAS_F32
            if (c < nbias) v += bias0[c];
            ((float*)out0)[(size_t)(r0 + i2) * ldc + c] = v;
          }
        }
      }
    }
  }
}

// fp32 -> bf16 convert, 4 elems/thread
__global__ __launch_bounds__(256)
void cvt_kernel(const float* __restrict__ in, unsigned short* __restrict__ out, int n)
{
  int i = (blockIdx.x * 256 + threadIdx.x) * 4;
  if (i < n) {
    float4 v = *(const float4*)(in + i);
    ushort4 o;
    o.x = f2bf(v.x); o.y = f2bf(v.y); o.z = f2bf(v.z); o.w = f2bf(v.w);
    *(ushort4*)(out + i) = o;
  }
}

// in fp32 [R][C] -> out bf16 [Cpad][Rpad], zero-filled pad. grid (Rpad/32, Cpad/32)
// omode 0: out row = c. omode 1/2: 16-col interleave (gate/up halves of WguT).
__global__ __launch_bounds__(256)
void wtrans_kernel(const float* __restrict__ in, unsigned short* __restrict__ out,
                   int R, int C, int Cpad, int Rpad, int omode)
{
  __shared__ float tile[32][33];
  int r0 = blockIdx.x * 32;   // in-row / out-col
  int c0 = blockIdx.y * 32;   // in-col / out-row
  int tid = threadIdx.x;
#pragma unroll
  for (int j = 0; j < 4; ++j) {
    int r = j * 8 + (tid >> 5), c = tid & 31;
    float v = 0.f;
    if (r0 + r < R && c0 + c < C) v = in[(size_t)(r0 + r) * C + c0 + c];
    tile[r][c] = v;
  }
  __syncthreads();
#pragma unroll
  for (int j = 0; j < 4; ++j) {
    int c = j * 8 + (tid >> 5), r = tid & 31;
    int oc = c0 + c;
    int orow = (omode == 0) ? oc
             : ((oc >> 4) * 32 + (oc & 15) + ((omode == 2) ? 16 : 0));
    out[(size_t)orow * Rpad + (r0 + r)] = f2bf(tile[r][c]);
  }
}

__device__ __forceinline__ float block_sum(float v, float* sm)
{
#pragma unroll
  for (int o = 32; o > 0; o >>= 1) v += __shfl_down(v, o, 64);
  int w = threadIdx.x >> 6;
  if ((threadIdx.x & 63) == 0) sm[w] = v;
  __syncthreads();
  float r = sm[0] + sm[1] + sm[2] + sm[3];
  __syncthreads();
  return r;
}

// row sums of kpT [4][1024][4096] -> ksum [4][1024]; grid 4096
__global__ __launch_bounds__(256)
void ksum_kernel(const unsigned short* __restrict__ kpT, float* __restrict__ ksum)
{
  __shared__ float sm[4];
  int row = blockIdx.x;
  const ushort4* src = (const ushort4*)(kpT + (size_t)row * SEQ);
  float s = 0.f;
#pragma unroll
  for (int j = 0; j < 4; ++j) {
    ushort4 v = src[threadIdx.x + j * 256];
    s += bf2f(v.x) + bf2f(v.y) + bf2f(v.z) + bf2f(v.w);
  }
  float tot = block_sum(s, sm);
  if (threadIdx.x == 0) ksum[row] = tot;
}

// y = LN(x + num/(den+eps)); den = qp . ksum  (fused). grid TOK, 256 thr
__global__ __launch_bounds__(256)
void ln1_kernel(const unsigned short* __restrict__ xb16, const unsigned short* __restrict__ num16,
                const unsigned short* __restrict__ qp, const float* __restrict__ ksum,
                const float* __restrict__ g1, const float* __restrict__ b1,
                unsigned short* __restrict__ yb)
{
  __shared__ float sm[4];
  int t = blockIdx.x, tid = threadIdx.x, b = t >> 12;
  ushort4 xv = ((const ushort4*)(xb16 + (size_t)t * DM))[tid];
  ushort4 nv = ((const ushort4*)(num16 + (size_t)t * DM))[tid];
  ushort4 qv = ((const ushort4*)(qp + (size_t)t * DM))[tid];
  float4 kv = ((const float4*)(ksum + (size_t)b * DM))[tid];
  float q0 = bf2f(qv.x), q1 = bf2f(qv.y), q2 = bf2f(qv.z), q3 = bf2f(qv.w);
  float den = block_sum(q0 * kv.x + q1 * kv.y + q2 * kv.z + q3 * kv.w, sm);
  float inv = 1.f / (den + 1e-6f);
  float r0 = bf2f(xv.x) + bf2f(nv.x) * inv, r1 = bf2f(xv.y) + bf2f(nv.y) * inv;
  float r2 = bf2f(xv.z) + bf2f(nv.z) * inv, r3 = bf2f(xv.w) + bf2f(nv.w) * inv;
  float s1 = block_sum(r0 + r1 + r2 + r3, sm);
  float s2 = block_sum(r0 * r0 + r1 * r1 + r2 * r2 + r3 * r3, sm);
  float mu = s1 * (1.f / 1024.f);
  float var = s2 * (1.f / 1024.f) - mu * mu;
  float rs = rsqrtf(var + 1e-5f);
  float4 gv = ((const float4*)g1)[tid];
  float4 bv = ((const float4*)b1)[tid];
  ushort4 o;
  o.x = f2bf((r0 - mu) * rs * gv.x + bv.x);
  o.y = f2bf((r1 - mu) * rs * gv.y + bv.y);
  o.z = f2bf((r2 - mu) * rs * gv.z + bv.z);
  o.w = f2bf((r3 - mu) * rs * gv.w + bv.w);
  ((ushort4*)(yb + (size_t)t * DM))[tid] = o;
}

// out = LN(y + ffn). grid TOK, 256 thr. ffn may alias out (row-local).
__global__ __launch_bounds__(256)
void ln2_kernel(const unsigned short* __restrict__ yb, const float* __restrict__ ffn,
                const float* __restrict__ g2, const float* __restrict__ b2,
                float* __restrict__ out)
{
  __shared__ float sm[4];
  int t = blockIdx.x, tid = threadIdx.x;
  ushort4 yv = ((const ushort4*)(yb + (size_t)t * DM))[tid];
  float4 fv = ((const float4*)(ffn + (size_t)t * DM))[tid];
  float r0 = bf2f(yv.x) + fv.x, r1 = bf2f(yv.y) + fv.y;
  float r2 = bf2f(yv.z) + fv.z, r3 = bf2f(yv.w) + fv.w;
  float s1 = block_sum(r0 + r1 + r2 + r3, sm);
  float s2 = block_sum(r0 * r0 + r1 * r1 + r2 * r2 + r3 * r3, sm);
  float mu = s1 * (1.f / 1024.f);
  float var = s2 * (1.f / 1024.f) - mu * mu;
  float rs = rsqrtf(var + 1e-5f);
  float4 gv = ((const float4*)g2)[tid];
  float4 bv = ((const float4*)b2)[tid];
  float4 o;
  o.x = (r0 - mu) * rs * gv.x + bv.x;
  o.y = (r1 - mu) * rs * gv.y + bv.y;
  o.z = (r2 - mu) * rs * gv.z + bv.z;
  o.w = (r3 - mu) * rs * gv.w + bv.w;
  ((float4*)(out + (size_t)t * DM))[tid] = o;
}

extern "C" void kernel_launch(void* const* d_in, const int* in_sizes, int n_in,
                              void* d_out, int out_size, void* d_ws, size_t ws_size,
                              hipStream_t stream)
{
  const float* x    = (const float*)d_in[0];
  const float* Wqkv = (const float*)d_in[1];
  const float* bqkv = (const float*)d_in[2];
  const float* Wg   = (const float*)d_in[3];
  const float* bg   = (const float*)d_in[4];
  const float* Wu   = (const float*)d_in[5];
  const float* bu   = (const float*)d_in[6];
  const float* Wd   = (const float*)d_in[7];
  const float* bd   = (const float*)d_in[8];
  const float* g1   = (const float*)d_in[9];
  const float* b1   = (const float*)d_in[10];
  const float* g2   = (const float*)d_in[11];
  const float* b2   = (const float*)d_in[12];
  float* out = (float*)d_out;

  // ---- workspace layout (~158.5 MiB total) ----
  char* ws = (char*)d_ws;
  size_t off = 0;
  auto alloc = [&](size_t bytes) {
    char* p = ws + off;
    off += (bytes + 255) & ~(size_t)255;
    return p;
  };
  unsigned short* WqkvT = (unsigned short*)alloc((size_t)NQKV * DM * 2);      //  6.3 MB
  unsigned short* WguT  = (unsigned short*)alloc((size_t)2 * FFHP * DM * 2);  // 11.5 MB (gate/up 16-col interleaved)
  unsigned short* WdT   = (unsigned short*)alloc((size_t)DM * FFHP * 2);      //  5.8 MB
  float*          ksum  = (float*)alloc((size_t)4 * DM * 4);                  // 16 KB
  unsigned short* xbyb  = (unsigned short*)alloc((size_t)TOK * DM * 2);       // 32 MB (xb then yb)
  unsigned short* kvT   = (unsigned short*)alloc((size_t)4 * DM * DM * 2);    //  8.4 MB
  char* R3 = alloc((size_t)3 * TOK * DM * 2);                                 // 96 MB
  unsigned short* qp  = (unsigned short*)(R3);
  unsigned short* kpT = (unsigned short*)(R3 + (size_t)TOK * DM * 2);
  unsigned short* vT  = (unsigned short*)(R3 + (size_t)2 * TOK * DM * 2);
  unsigned short* hbuf = (unsigned short*)(R3);     // [TOK][FFHP] 92.3 MB, aliases qp/kpT/vT (dead after ln1)
  unsigned short* xb = xbyb;
  unsigned short* yb = xbyb;
  unsigned short* num = (unsigned short*)d_out;     // bf16 scratch in d_out; dead after ln1
  float* ffn = (float*)d_out;                       // fp32 scratch; ln2 reads+overwrites row-local

  dim3 blk(256), blk5(512);

  // 1. x -> bf16
  cvt_kernel<<<dim3(TOK * DM / 1024), blk, 0, stream>>>(x, xb, TOK * DM);
  // 2. weight transpose+convert (+pad; gate/up interleaved into WguT)
  wtrans_kernel<<<dim3(32, 96), blk, 0, stream>>>(Wqkv, WqkvT, 1024, 3072, 3072, 1024, 0);
  wtrans_kernel<<<dim3(32, 88), blk, 0, stream>>>(Wg, WguT, 1024, FFH, FFHP, 1024, 1);
  wtrans_kernel<<<dim3(32, 88), blk, 0, stream>>>(Wu, WguT, 1024, FFH, FFHP, 1024, 2);
  wtrans_kernel<<<dim3(88, 32), blk, 0, stream>>>(Wd, WdT, FFH, 1024, 1024, FFHP, 0);
  // 3. QKV GEMM: qp[s][d] (elu+1), kpT[d][s] (elu+1), vT[d][s]  [128^2 legacy]
  gemm_kernel<M_QKV><<<dim3(NQKV / 128, TOK / 128), blk, 0, stream>>>(
      xb, WqkvT, 1024, 1024, 1024, 0, 0, 0, 0, qp, kpT, vT, bqkv, NQKV);
  // 4. k_sum[b][d]
  ksum_kernel<<<dim3(4096), blk, 0, stream>>>(kpT, ksum);
  // 5. kvT[b][e][d] = sum_s v[s,e] kp[s,d]   [128^2 legacy]
  gemm_kernel<M_BF16><<<dim3(8, 8, 4), blk, 0, stream>>>(
      vT, kpT, 4096, 4096, 4096, 1024,
      (long)DM * SEQ, (long)DM * SEQ, (long)DM * DM,
      kvT, nullptr, nullptr, nullptr, 0);
  // 6. num[b][s][e] = qp[s,:] . kv[:,e]  (BT = kvT) -> d_out (bf16)  [256^2 8-phase]
  gemm256_kernel<G_NUM><<<dim3(4, 16, 4), blk5, 0, stream>>>(
      qp, kvT, 1024, 1024, 1024, 1024,
      (long)SEQ * DM, (long)DM * DM, (long)SEQ * DM,
      num, nullptr, nullptr, 0);
  // 7. LN1 (fused den + attn + residual), y in bf16 (overwrites xb in place)
  ln1_kernel<<<dim3(TOK), blk, 0, stream>>>(xb, num, qp, ksum, g1, b1, yb);
  // 8. h = silu(y@Wg+bg) * (y@Wu+bu), fused 256^2 8-phase over interleaved WguT
  gemm256_kernel<G_GATEUP><<<dim3(2 * FFHP / 256, TOK / 256), blk5, 0, stream>>>(
      yb, WguT, 1024, DM, DM, FFHP, 0, 0, 0, hbuf, bg, bu, FFH);
  // 9. ffn = h @ Wd + bd (fp32) -> d_out  [256^2 8-phase]
  gemm256_kernel<G_BIAS_F32><<<dim3(DM / 256, TOK / 256), blk5, 0, stream>>>(
      hbuf, WdT, FFHP, FFHP, FFHP, DM, 0, 0, 0, ffn, bd, nullptr, DM);
  // 10. out = LN(y + ffn)  (reads+overwrites d_out row-locally)
  ln2_kernel<<<dim3(TOK), blk, 0, stream>>>(yb, ffn, g2, b2, out);

  (void)in_sizes; (void)n_in; (void)out_size; (void)ws_size;
}

// Round 6
// 741.172 us; speedup vs baseline: 1.1322x; 1.0628x over previous
//
#include <hip/hip_runtime.h>

#define SEQ 4096
#define TOK 16384            // B*S
#define DM 1024
#define NQKV 3072
#define FFH 2730
#define FFHP 2816            // padded to multiple of 128

typedef __bf16 bf16x8 __attribute__((ext_vector_type(8)));
typedef float f32x4 __attribute__((ext_vector_type(4)));
typedef unsigned short u16x8 __attribute__((ext_vector_type(8)));

__device__ __forceinline__ unsigned short f2bf(float f) {
  union { float f; unsigned u; } v; v.f = f;
  unsigned r = v.u + 0x7fffu + ((v.u >> 16) & 1u);
  return (unsigned short)(r >> 16);
}
__device__ __forceinline__ float bf2f(unsigned short h) {
  union { unsigned u; float f; } v; v.u = ((unsigned)h) << 16;
  return v.f;
}

__device__ __forceinline__ void xcd_swizzle(int& bx, int& by) {
  const int gx = gridDim.x, gy = gridDim.y;
  const int chunk = gy >> 3;            // power of 2 in all our launches
  const int csh = __ffs(chunk) - 1;
  const int lin = by * gx + bx;
  const int xcd = lin & 7, j = lin >> 3;
  by = xcd * chunk + (j & (chunk - 1));
  bx = j >> csh;
}

enum { M_QKV = 0, M_BF16 = 1, M_NUM = 2, M_BIAS_F32 = 5 };

// ---------------- legacy 128x128 kernel (kv GEMM only) ----------------
template<int MODE>
__global__ __launch_bounds__(256)
void gemm_kernel(const unsigned short* __restrict__ A,
                 const unsigned short* __restrict__ BT,
                 int K, int lda, int ldb, int ldc,
                 long zsA, long zsB, long zsC,
                 void* __restrict__ out0, void* __restrict__ out1, void* __restrict__ out2,
                 const float* __restrict__ bias, int nbias)
{
  __shared__ unsigned short As[2][128 * 64];
  __shared__ unsigned short Bs[2][128 * 64];
  const int tid  = threadIdx.x;
  const int wave = tid >> 6, lane = tid & 63;
  const int quad = lane >> 4, l16 = lane & 15;
  const int bz = blockIdx.z;
  int bx = blockIdx.x, by = blockIdx.y;
  xcd_swizzle(bx, by);

  const unsigned short* Ab = A + (size_t)zsA * bz + (size_t)by * 128 * lda;
  const unsigned short* Bb = BT + (size_t)zsB * bz + (size_t)bx * 128 * ldb;

  f32x4 acc[4][4] = {};

  const int srow   = lane >> 3;
  const int scol_g = (((lane & 7) ^ srow) * 8);
  const int axor   = l16 & 7;

  auto stage = [&](int buf, int k0) {
#pragma unroll
    for (int j = 0; j < 4; ++j) {
      int c = wave * 4 + j;
      const unsigned short* sa = Ab + (size_t)(c * 8 + srow) * lda + k0 + scol_g;
      __builtin_amdgcn_global_load_lds((__attribute__((address_space(1))) void*)sa,
          (__attribute__((address_space(3))) void*)(As[buf] + c * 512), 16, 0, 0);
      const unsigned short* sb = Bb + (size_t)(c * 8 + srow) * ldb + k0 + scol_g;
      __builtin_amdgcn_global_load_lds((__attribute__((address_space(1))) void*)sb,
          (__attribute__((address_space(3))) void*)(Bs[buf] + c * 512), 16, 0, 0);
    }
  };

  const int NIT = K >> 6;
  stage(0, 0);
  int cur = 0;
  for (int it = 0; it < NIT; ++it) {
    __builtin_amdgcn_s_waitcnt(0);
    __syncthreads();
    if (it + 1 < NIT) stage(cur ^ 1, (it + 1) << 6);
#pragma unroll
    for (int kk = 0; kk < 64; kk += 32) {
      bf16x8 af[4], bfr[4];
#pragma unroll
      for (int mt = 0; mt < 4; ++mt)
        af[mt] = *(const bf16x8*)(As[cur] + ((wave >> 1) * 64 + mt * 16 + l16) * 64
                                     + ((((kk >> 3) + quad) ^ axor) * 8));
#pragma unroll
      for (int nt = 0; nt < 4; ++nt)
        bfr[nt] = *(const bf16x8*)(Bs[cur] + ((wave & 1) * 64 + nt * 16 + l16) * 64
                                      + ((((kk >> 3) + quad) ^ axor) * 8));
#pragma unroll
      for (int mt = 0; mt < 4; ++mt)
#pragma unroll
        for (int nt = 0; nt < 4; ++nt)
          acc[mt][nt] = __builtin_amdgcn_mfma_f32_16x16x32_bf16(af[mt], bfr[nt], acc[mt][nt], 0, 0, 0);
    }
    cur ^= 1;
  }

#pragma unroll
  for (int mt = 0; mt < 4; ++mt) {
#pragma unroll
    for (int nt = 0; nt < 4; ++nt) {
      const int r0 = by * 128 + (wave >> 1) * 64 + mt * 16 + quad * 4;
      const int c  = bx * 128 + (wave & 1) * 64 + nt * 16 + l16;
#pragma unroll
      for (int i = 0; i < 4; ++i) {
        const int r = r0 + i;
        float val = acc[mt][nt][i];
        if (MODE == M_BF16 || MODE == M_NUM) {
          ((unsigned short*)out0)[(size_t)zsC * bz + (size_t)r * ldc + c] = f2bf(val);
        } else {
          if (c < nbias) val += bias[c];
          ((float*)out0)[(size_t)r * ldc + c] = val;
        }
      }
    }
  }
}

// ---------------- 256x256 8-phase kernel ----------------
// BM=BN=256, BK=64, 8 waves (2M x 4N), per-wave 128x64 output, dbuf LDS 128KiB.
// Gray order (0,0)->(0,1)->(1,1)->(1,0): re-reads the SMALLER (B) quadrant ->
// 28 ds_read_b128/wave/K-tile (vs 32 with the A-re-reading order); LDS read
// time (~2100cyc/CU/K-tile) is at parity with MFMA (~2480cyc) so reads count.
// Stage slots derived from last-read table (buf0: A0@P1,B1@P2,A1@P3,B0@P4;
// buf1 same +4): each region restaged >=1 barrier after its last read; WAITV(4)
// at P4/P8 drains exactly the 8 loads the next buffer needs (12 outstanding,
// keep newest 4). Tail iteration: stages skipped -> WAITV(0) (also guarantees
// no in-flight global_load_lds when G_QKV reuses LDS as transpose scratch).
enum { G_GATEUP = 0, G_NUM = 1, G_BIAS_F32 = 2, G_QKV = 3 };

#define MBAR() asm volatile("s_barrier" ::: "memory")
#define WAITV(N) asm volatile("s_waitcnt vmcnt(" #N ")" ::: "memory")

#define LDS_A(BUF, QM) do {                                                   \
    _Pragma("unroll")                                                         \
    for (int mt = 0; mt < 4; ++mt) {                                          \
      _Pragma("unroll")                                                       \
      for (int k2 = 0; k2 < 2; ++k2)                                          \
        af[mt][k2] = *(const bf16x8*)(SH[BUF] +                               \
            (wm * 128 + ((QM) * 4 + mt) * 16 + l16) * 64 +                    \
            (((k2 * 4 + quad) ^ axor) * 8));                                  \
    }                                                                         \
  } while (0)

#define LDS_B(BUF, QN) do {                                                   \
    _Pragma("unroll")                                                         \
    for (int nt = 0; nt < 2; ++nt) {                                          \
      _Pragma("unroll")                                                       \
      for (int k2 = 0; k2 < 2; ++k2)                                          \
        bfr[nt][k2] = *(const bf16x8*)(SH[2 + (BUF)] +                        \
            (wn * 64 + ((QN) * 2 + nt) * 16 + l16) * 64 +                     \
            (((k2 * 4 + quad) ^ axor) * 8));                                  \
    }                                                                         \
  } while (0)

#define MMAQ(QM, QN) do {                                                     \
    _Pragma("unroll")                                                         \
    for (int mt = 0; mt < 4; ++mt) {                                          \
      _Pragma("unroll")                                                       \
      for (int nt = 0; nt < 2; ++nt) {                                        \
        _Pragma("unroll")                                                     \
        for (int k2 = 0; k2 < 2; ++k2)                                        \
          acc[(QM) * 4 + mt][(QN) * 2 + nt] =                                 \
              __builtin_amdgcn_mfma_f32_16x16x32_bf16(af[mt][k2], bfr[nt][k2],\
                  acc[(QM) * 4 + mt][(QN) * 2 + nt], 0, 0, 0);                \
      }                                                                       \
    }                                                                         \
  } while (0)

#define PHASE(BUF, QM, QN, LA, LB, STAGE, WAIT) do {                          \
    if (LA) LDS_A(BUF, QM);                                                   \
    if (LB) LDS_B(BUF, QN);                                                   \
    STAGE                                                                     \
    MBAR();                                                                   \
    __builtin_amdgcn_sched_barrier(0);                                        \
    __builtin_amdgcn_s_setprio(1);                                            \
    MMAQ(QM, QN);                                                             \
    __builtin_amdgcn_s_setprio(0);                                            \
    WAIT                                                                      \
    MBAR();                                                                   \
  } while (0)

template<int MODE>
__global__ __launch_bounds__(512, 2)
void gemm256_kernel(const unsigned short* __restrict__ A,
                    const unsigned short* __restrict__ BT,
                    int K, int lda, int ldb, int ldc,
                    long zsA, long zsB, long zsC,
                    void* __restrict__ out0,
                    void* __restrict__ out1, void* __restrict__ out2,
                    const float* __restrict__ bias0,
                    const float* __restrict__ bias1,
                    int nbias)
{
  // unified LDS: SH[0..1] = A dbuf, SH[2..3] = B dbuf; 128KiB contiguous so
  // G_QKV can reuse it as a 256x256 bf16 transpose scratch after the loop.
  __shared__ unsigned short SH[4][256 * 64];
  const int tid  = threadIdx.x;
  const int wave = tid >> 6, lane = tid & 63;
  const int quad = lane >> 4, l16 = lane & 15;
  const int wm = wave >> 2, wn = wave & 3;
  const int bz = blockIdx.z;
  int bx = blockIdx.x, by = blockIdx.y;
  xcd_swizzle(bx, by);

  const unsigned short* Ab = A + (size_t)zsA * bz + (size_t)by * 256 * lda;
  const unsigned short* Bb = BT + (size_t)zsB * bz + (size_t)bx * 256 * ldb;

  f32x4 acc[8][4] = {};

  const int srow = lane >> 3;                 // row within 8-row chunk
  const int sxor = ((lane & 7) ^ srow) * 8;   // pre-swizzled global col block
  const int axor = l16 & 7;

  // Per-wave staging pointers/chunks (2 parts x 2 loads each).
  // A part0 chunks {0-7,16-23} (= Q0 rows of both wm), part1 {8-15,24-31}.
  // B part0 chunks {0-3,8-11,16-19,24-27} (= Q0 cols of all wn), part1 +4.
  const unsigned short* pA[2][2];
  const unsigned short* pB[2][2];
  int cA[2][2], cB[2][2];
#pragma unroll
  for (int part = 0; part < 2; ++part) {
#pragma unroll
    for (int j = 0; j < 2; ++j) {
      int idx = wave * 2 + j;                 // 0..15
      int ca = ((idx & 8) ? idx + 8 : idx) + part * 8;
      int cb = (idx >> 2) * 8 + (idx & 3) + part * 4;
      cA[part][j] = ca; cB[part][j] = cb;
      pA[part][j] = Ab + (size_t)(ca * 8 + srow) * lda + sxor;
      pB[part][j] = Bb + (size_t)(cb * 8 + srow) * ldb + sxor;
    }
  }

  auto stageA = [&](int buf, int part, int tile) {
    const int k0 = tile << 6;
#pragma unroll
    for (int j = 0; j < 2; ++j)
      __builtin_amdgcn_global_load_lds(
          (__attribute__((address_space(1))) void*)(pA[part][j] + k0),
          (__attribute__((address_space(3))) void*)(SH[buf] + cA[part][j] * 512), 16, 0, 0);
  };
  auto stageB = [&](int buf, int part, int tile) {
    const int k0 = tile << 6;
#pragma unroll
    for (int j = 0; j < 2; ++j)
      __builtin_amdgcn_global_load_lds(
          (__attribute__((address_space(1))) void*)(pB[part][j] + k0),
          (__attribute__((address_space(3))) void*)(SH[2 + buf] + cB[part][j] * 512), 16, 0, 0);
  };

  // prologue: buf0 full tile0 (8 loads) + buf1 A0,A1 of tile1 (4 loads)
  stageA(0, 0, 0); stageB(0, 0, 0); stageA(0, 1, 0); stageB(0, 1, 0);
  stageA(1, 0, 1); stageA(1, 1, 1);
  WAITV(4);                      // tile0's 8 loads landed
  MBAR();

  bf16x8 af[4][2], bfr[2][2];
  const int NT = K >> 6;         // even, >= 4 for all our shapes
  for (int i = 0; i < NT; i += 2) {
    const int t2s = (i + 2 < NT);    // == (i+3 < NT) since NT even
    // buf0 = tile i, Gray order (0,0)->(0,1)->(1,1)->(1,0); buf1 = tile i+1
    PHASE(0, 0, 0, 1, 1, { stageB(1, 0, i + 1); }, {});              // P1
    PHASE(0, 0, 1, 0, 1, { stageB(1, 1, i + 1); }, {});              // P2
    PHASE(0, 1, 1, 1, 0, { if (t2s) stageA(0, 0, i + 2); }, {});     // P3
    PHASE(0, 1, 0, 0, 1, { if (t2s) stageB(0, 1, i + 2); },
                         { if (t2s) { WAITV(4); } else { WAITV(0); } }); // P4
    PHASE(1, 0, 0, 1, 1, { if (t2s) stageA(0, 1, i + 2); }, {});     // P5
    PHASE(1, 0, 1, 0, 1, { if (t2s) stageB(0, 0, i + 2); }, {});     // P6
    PHASE(1, 1, 1, 1, 0, { if (t2s) stageA(1, 0, i + 3); }, {});     // P7
    PHASE(1, 1, 0, 0, 1, { if (t2s) stageA(1, 1, i + 3); },
                         { if (t2s) { WAITV(4); } else { WAITV(0); } }); // P8
  }

  // ---- epilogue ----
  if (MODE == G_GATEUP) {
    // BT is 16-col-interleaved [gate16|up16]*; n-frag pairs (0,1),(2,3) hold
    // matching gate/up columns -> silu(g)*u is wave-local.
#pragma unroll
    for (int mt = 0; mt < 8; ++mt) {
      const int r0 = by * 256 + wm * 128 + mt * 16 + quad * 4;
#pragma unroll
      for (int p = 0; p < 2; ++p) {
        const int hc = bx * 128 + wn * 32 + p * 16 + l16;
        const float bgv = (hc < nbias) ? bias0[hc] : 0.f;
        const float buv = (hc < nbias) ? bias1[hc] : 0.f;
#pragma unroll
        for (int i2 = 0; i2 < 4; ++i2) {
          float g = acc[mt][2 * p][i2] + bgv;
          float u = acc[mt][2 * p + 1][i2] + buv;
          float hv = g / (1.f + __expf(-g)) * u;
          ((unsigned short*)out0)[(size_t)(r0 + i2) * ldc + hc] = f2bf(hv);
        }
      }
    }
  } else if (MODE == G_QKV) {
    const int b = (by * 256) >> 12, s0 = (by * 256) & 4095;
    if (bx < 4) {
      // q: elu+1, row-major [s][d] direct stores (16-lane 32B chunks)
#pragma unroll
      for (int mt = 0; mt < 8; ++mt) {
#pragma unroll
        for (int nt = 0; nt < 4; ++nt) {
          const int r0 = by * 256 + wm * 128 + mt * 16 + quad * 4;
          const int c  = bx * 256 + wn * 64 + nt * 16 + l16;
          const float bv = bias0[c];
#pragma unroll
          for (int i2 = 0; i2 < 4; ++i2) {
            float v = acc[mt][nt][i2] + bv;
            float e = v > 0.f ? v + 1.f : __expf(v);
            ((unsigned short*)out0)[(size_t)(r0 + i2) * DM + c] = f2bf(e);
          }
        }
      }
    } else {
      // k/v: LDS transpose to [c][s] (swizzled 8-elem blocks), then fully
      // coalesced 512B-row stores. Safe: final P8 barrier passed by all waves
      // and tail WAITV(0) guarantees no in-flight global_load_lds into SH.
      const bool isK = (bx < 8);
      unsigned short* lsc = &SH[0][0];           // 256*256 shorts = 128KiB
#pragma unroll
      for (int mt = 0; mt < 8; ++mt) {
        const int sb = wm * 128 + mt * 16 + quad * 4;   // s_loc base (4-aligned)
#pragma unroll
        for (int nt = 0; nt < 4; ++nt) {
          const int cl = wn * 64 + nt * 16 + l16;       // c_loc 0..255
          const float bv = bias0[bx * 256 + cl];
          ushort4 o;
#pragma unroll
          for (int i2 = 0; i2 < 4; ++i2) {
            float v = acc[mt][nt][i2] + bv;
            if (isK) v = v > 0.f ? v + 1.f : __expf(v);
            ((unsigned short*)&o)[i2] = f2bf(v);
          }
          *(ushort4*)(lsc + cl * 256 + (((sb >> 3) ^ (cl & 31)) << 3) + (sb & 7)) = o;
        }
      }
      __syncthreads();
      unsigned short* obase = isK ? (unsigned short*)out1 : (unsigned short*)out2;
      const int coff = (isK ? (bx - 4) : (bx - 8)) * 256;
      const int l32 = tid & 31;
#pragma unroll
      for (int pass = 0; pass < 16; ++pass) {
        const int c = pass * 16 + (tid >> 5);
        u16x8 v = *(const u16x8*)(lsc + c * 256 + ((l32 ^ (c & 31)) << 3));
        *(u16x8*)(obase + ((size_t)b * DM + coff + c) * SEQ + s0 + l32 * 8) = v;
      }
    }
  } else {
#pragma unroll
    for (int mt = 0; mt < 8; ++mt) {
#pragma unroll
      for (int nt = 0; nt < 4; ++nt) {
        const int r0 = by * 256 + wm * 128 + mt * 16 + quad * 4;
        const int c  = bx * 256 + wn * 64 + nt * 16 + l16;
#pragma unroll
        for (int i2 = 0; i2 < 4; ++i2) {
          float v = acc[mt][nt][i2];
          if (MODE == G_NUM) {
            ((unsigned short*)out0)[(size_t)zsC * bz + (size_t)(r0 + i2) * ldc + c] = f2bf(v);
          } else {  // G_BIAS_F32
            if (c < nbias) v += bias0[c];
            ((float*)out0)[(size_t)(r0 + i2) * ldc + c] = v;
          }
        }
      }
    }
  }
}

// fp32 -> bf16 convert, 4 elems/thread
__global__ __launch_bounds__(256)
void cvt_kernel(const float* __restrict__ in, unsigned short* __restrict__ out, int n)
{
  int i = (blockIdx.x * 256 + threadIdx.x) * 4;
  if (i < n) {
    float4 v = *(const float4*)(in + i);
    ushort4 o;
    o.x = f2bf(v.x); o.y = f2bf(v.y); o.z = f2bf(v.z); o.w = f2bf(v.w);
    *(ushort4*)(out + i) = o;
  }
}

// in fp32 [R][C] -> out bf16 [Cpad][Rpad], zero-filled pad. grid (Rpad/32, Cpad/32)
// omode 0: out row = c. omode 1/2: 16-col interleave (gate/up halves of WguT).
__global__ __launch_bounds__(256)
void wtrans_kernel(const float* __restrict__ in, unsigned short* __restrict__ out,
                   int R, int C, int Cpad, int Rpad, int omode)
{
  __shared__ float tile[32][33];
  int r0 = blockIdx.x * 32;   // in-row / out-col
  int c0 = blockIdx.y * 32;   // in-col / out-row
  int tid = threadIdx.x;
#pragma unroll
  for (int j = 0; j < 4; ++j) {
    int r = j * 8 + (tid >> 5), c = tid & 31;
    float v = 0.f;
    if (r0 + r < R && c0 + c < C) v = in[(size_t)(r0 + r) * C + c0 + c];
    tile[r][c] = v;
  }
  __syncthreads();
#pragma unroll
  for (int j = 0; j < 4; ++j) {
    int c = j * 8 + (tid >> 5), r = tid & 31;
    int oc = c0 + c;
    int orow = (omode == 0) ? oc
             : ((oc >> 4) * 32 + (oc & 15) + ((omode == 2) ? 16 : 0));
    out[(size_t)orow * Rpad + (r0 + r)] = f2bf(tile[r][c]);
  }
}

__device__ __forceinline__ float block_sum(float v, float* sm)
{
#pragma unroll
  for (int o = 32; o > 0; o >>= 1) v += __shfl_down(v, o, 64);
  int w = threadIdx.x >> 6;
  if ((threadIdx.x & 63) == 0) sm[w] = v;
  __syncthreads();
  float r = sm[0] + sm[1] + sm[2] + sm[3];
  __syncthreads();
  return r;
}

// row sums of kpT [4][1024][4096] -> ksum [4][1024]; grid 4096
__global__ __launch_bounds__(256)
void ksum_kernel(const unsigned short* __restrict__ kpT, float* __restrict__ ksum)
{
  __shared__ float sm[4];
  int row = blockIdx.x;
  const ushort4* src = (const ushort4*)(kpT + (size_t)row * SEQ);
  float s = 0.f;
#pragma unroll
  for (int j = 0; j < 4; ++j) {
    ushort4 v = src[threadIdx.x + j * 256];
    s += bf2f(v.x) + bf2f(v.y) + bf2f(v.z) + bf2f(v.w);
  }
  float tot = block_sum(s, sm);
  if (threadIdx.x == 0) ksum[row] = tot;
}

// y = LN(x + num/(den+eps)); den = qp . ksum  (fused). grid TOK, 256 thr
__global__ __launch_bounds__(256)
void ln1_kernel(const unsigned short* __restrict__ xb16, const unsigned short* __restrict__ num16,
                const unsigned short* __restrict__ qp, const float* __restrict__ ksum,
                const float* __restrict__ g1, const float* __restrict__ b1,
                unsigned short* __restrict__ yb)
{
  __shared__ float sm[4];
  int t = blockIdx.x, tid = threadIdx.x, b = t >> 12;
  ushort4 xv = ((const ushort4*)(xb16 + (size_t)t * DM))[tid];
  ushort4 nv = ((const ushort4*)(num16 + (size_t)t * DM))[tid];
  ushort4 qv = ((const ushort4*)(qp + (size_t)t * DM))[tid];
  float4 kv = ((const float4*)(ksum + (size_t)b * DM))[tid];
  float q0 = bf2f(qv.x), q1 = bf2f(qv.y), q2 = bf2f(qv.z), q3 = bf2f(qv.w);
  float den = block_sum(q0 * kv.x + q1 * kv.y + q2 * kv.z + q3 * kv.w, sm);
  float inv = 1.f / (den + 1e-6f);
  float r0 = bf2f(xv.x) + bf2f(nv.x) * inv, r1 = bf2f(xv.y) + bf2f(nv.y) * inv;
  float r2 = bf2f(xv.z) + bf2f(nv.z) * inv, r3 = bf2f(xv.w) + bf2f(nv.w) * inv;
  float s1 = block_sum(r0 + r1 + r2 + r3, sm);
  float s2 = block_sum(r0 * r0 + r1 * r1 + r2 * r2 + r3 * r3, sm);
  float mu = s1 * (1.f / 1024.f);
  float var = s2 * (1.f / 1024.f) - mu * mu;
  float rs = rsqrtf(var + 1e-5f);
  float4 gv = ((const float4*)g1)[tid];
  float4 bv = ((const float4*)b1)[tid];
  ushort4 o;
  o.x = f2bf((r0 - mu) * rs * gv.x + bv.x);
  o.y = f2bf((r1 - mu) * rs * gv.y + bv.y);
  o.z = f2bf((r2 - mu) * rs * gv.z + bv.z);
  o.w = f2bf((r3 - mu) * rs * gv.w + bv.w);
  ((ushort4*)(yb + (size_t)t * DM))[tid] = o;
}

// out = LN(y + ffn). grid TOK, 256 thr. ffn may alias out (row-local).
__global__ __launch_bounds__(256)
void ln2_kernel(const unsigned short* __restrict__ yb, const float* __restrict__ ffn,
                const float* __restrict__ g2, const float* __restrict__ b2,
                float* __restrict__ out)
{
  __shared__ float sm[4];
  int t = blockIdx.x, tid = threadIdx.x;
  ushort4 yv = ((const ushort4*)(yb + (size_t)t * DM))[tid];
  float4 fv = ((const float4*)(ffn + (size_t)t * DM))[tid];
  float r0 = bf2f(yv.x) + fv.x, r1 = bf2f(yv.y) + fv.y;
  float r2 = bf2f(yv.z) + fv.z, r3 = bf2f(yv.w) + fv.w;
  float s1 = block_sum(r0 + r1 + r2 + r3, sm);
  float s2 = block_sum(r0 * r0 + r1 * r1 + r2 * r2 + r3 * r3, sm);
  float mu = s1 * (1.f / 1024.f);
  float var = s2 * (1.f / 1024.f) - mu * mu;
  float rs = rsqrtf(var + 1e-5f);
  float4 gv = ((const float4*)g2)[tid];
  float4 bv = ((const float4*)b2)[tid];
  float4 o;
  o.x = (r0 - mu) * rs * gv.x + bv.x;
  o.y = (r1 - mu) * rs * gv.y + bv.y;
  o.z = (r2 - mu) * rs * gv.z + bv.z;
  o.w = (r3 - mu) * rs * gv.w + bv.w;
  ((float4*)(out + (size_t)t * DM))[tid] = o;
}

extern "C" void kernel_launch(void* const* d_in, const int* in_sizes, int n_in,
                              void* d_out, int out_size, void* d_ws, size_t ws_size,
                              hipStream_t stream)
{
  const float* x    = (const float*)d_in[0];
  const float* Wqkv = (const float*)d_in[1];
  const float* bqkv = (const float*)d_in[2];
  const float* Wg   = (const float*)d_in[3];
  const float* bg   = (const float*)d_in[4];
  const float* Wu   = (const float*)d_in[5];
  const float* bu   = (const float*)d_in[6];
  const float* Wd   = (const float*)d_in[7];
  const float* bd   = (const float*)d_in[8];
  const float* g1   = (const float*)d_in[9];
  const float* b1   = (const float*)d_in[10];
  const float* g2   = (const float*)d_in[11];
  const float* b2   = (const float*)d_in[12];
  float* out = (float*)d_out;

  // ---- workspace layout (~158.5 MiB total) ----
  char* ws = (char*)d_ws;
  size_t off = 0;
  auto alloc = [&](size_t bytes) {
    char* p = ws + off;
    off += (bytes + 255) & ~(size_t)255;
    return p;
  };
  unsigned short* WqkvT = (unsigned short*)alloc((size_t)NQKV * DM * 2);      //  6.3 MB
  unsigned short* WguT  = (unsigned short*)alloc((size_t)2 * FFHP * DM * 2);  // 11.5 MB (gate/up 16-col interleaved)
  unsigned short* WdT   = (unsigned short*)alloc((size_t)DM * FFHP * 2);      //  5.8 MB
  float*          ksum  = (float*)alloc((size_t)4 * DM * 4);                  // 16 KB
  unsigned short* xbyb  = (unsigned short*)alloc((size_t)TOK * DM * 2);       // 32 MB (xb then yb)
  unsigned short* kvT   = (unsigned short*)alloc((size_t)4 * DM * DM * 2);    //  8.4 MB
  char* R3 = alloc((size_t)3 * TOK * DM * 2);                                 // 96 MB
  unsigned short* qp  = (unsigned short*)(R3);
  unsigned short* kpT = (unsigned short*)(R3 + (size_t)TOK * DM * 2);
  unsigned short* vT  = (unsigned short*)(R3 + (size_t)2 * TOK * DM * 2);
  unsigned short* hbuf = (unsigned short*)(R3);     // [TOK][FFHP] 92.3 MB, aliases qp/kpT/vT (dead after ln1)
  unsigned short* xb = xbyb;
  unsigned short* yb = xbyb;
  unsigned short* num = (unsigned short*)d_out;     // bf16 scratch in d_out; dead after ln1
  float* ffn = (float*)d_out;                       // fp32 scratch; ln2 reads+overwrites row-local

  dim3 blk(256), blk5(512);

  // 1. x -> bf16
  cvt_kernel<<<dim3(TOK * DM / 1024), blk, 0, stream>>>(x, xb, TOK * DM);
  // 2. weight transpose+convert (+pad; gate/up interleaved into WguT)
  wtrans_kernel<<<dim3(32, 96), blk, 0, stream>>>(Wqkv, WqkvT, 1024, 3072, 3072, 1024, 0);
  wtrans_kernel<<<dim3(32, 88), blk, 0, stream>>>(Wg, WguT, 1024, FFH, FFHP, 1024, 1);
  wtrans_kernel<<<dim3(32, 88), blk, 0, stream>>>(Wu, WguT, 1024, FFH, FFHP, 1024, 2);
  wtrans_kernel<<<dim3(88, 32), blk, 0, stream>>>(Wd, WdT, FFH, 1024, 1024, FFHP, 0);
  // 3. QKV GEMM: qp[s][d] (elu+1), kpT[d][s] (elu+1), vT[d][s]
  //    [256^2 8-phase; k/v via LDS-transposed coalesced stores]
  gemm256_kernel<G_QKV><<<dim3(NQKV / 256, TOK / 256), blk5, 0, stream>>>(
      xb, WqkvT, 1024, 1024, 1024, 0, 0, 0, 0, qp, kpT, vT, bqkv, nullptr, NQKV);
  // 4. k_sum[b][d]
  ksum_kernel<<<dim3(4096), blk, 0, stream>>>(kpT, ksum);
  // 5. kvT[b][e][d] = sum_s v[s,e] kp[s,d]   [128^2 legacy: grid must stay 256 blocks]
  gemm_kernel<M_BF16><<<dim3(8, 8, 4), blk, 0, stream>>>(
      vT, kpT, 4096, 4096, 4096, 1024,
      (long)DM * SEQ, (long)DM * SEQ, (long)DM * DM,
      kvT, nullptr, nullptr, nullptr, 0);
  // 6. num[b][s][e] = qp[s,:] . kv[:,e]  (BT = kvT) -> d_out (bf16)  [256^2 8-phase]
  gemm256_kernel<G_NUM><<<dim3(4, 16, 4), blk5, 0, stream>>>(
      qp, kvT, 1024, 1024, 1024, 1024,
      (long)SEQ * DM, (long)DM * DM, (long)SEQ * DM,
      num, nullptr, nullptr, nullptr, nullptr, 0);
  // 7. LN1 (fused den + attn + residual), y in bf16 (overwrites xb in place)
  ln1_kernel<<<dim3(TOK), blk, 0, stream>>>(xb, num, qp, ksum, g1, b1, yb);
  // 8. h = silu(y@Wg+bg) * (y@Wu+bu), fused 256^2 8-phase over interleaved WguT
  gemm256_kernel<G_GATEUP><<<dim3(2 * FFHP / 256, TOK / 256), blk5, 0, stream>>>(
      yb, WguT, 1024, DM, DM, FFHP, 0, 0, 0, hbuf, nullptr, nullptr, bg, bu, FFH);
  // 9. ffn = h @ Wd + bd (fp32) -> d_out  [256^2 8-phase]
  gemm256_kernel<G_BIAS_F32><<<dim3(DM / 256, TOK / 256), blk5, 0, stream>>>(
      hbuf, WdT, FFHP, FFHP, FFHP, DM, 0, 0, 0, ffn, nullptr, nullptr, bd, nullptr, DM);
  // 10. out = LN(y + ffn)  (reads+overwrites d_out row-locally)
  ln2_kernel<<<dim3(TOK), blk, 0, stream>>>(yb, ffn, g2, b2, out);

  (void)in_sizes; (void)n_in; (void)out_size; (void)ws_size;
}